// Round 7
// baseline (176.349 us; speedup 1.0000x reference)
//
#include <hip/hip_runtime.h>
#include <hip/hip_bf16.h>

typedef __bf16 bf16x8 __attribute__((ext_vector_type(8)));
typedef float floatx4 __attribute__((ext_vector_type(4)));

__device__ __forceinline__ unsigned short f2bf(float f) {
  __bf16 b = (__bf16)f;
  return __builtin_bit_cast(unsigned short, b);
}

// ---------------------------------------------------------------------------
// Kernel 1: decode w1 bits -> bf16 {-1,0,+1} in MFMA-FRAGMENT-TRANSPOSED order:
//   w1t[(kq*256 + row)*8 + k]  holds W[row][kq*8 + k],  kq in [0,104)
// (K padded 784 -> 832 with zeros). Fragment rows for one (chunk, quad, wave)
// are 16 consecutive rows = 256 contiguous bytes -> direct-to-VGPR coalesced.
// ---------------------------------------------------------------------------
__global__ void decode_w1_kernel(const int* __restrict__ w1p,
                                 const int* __restrict__ m1p,
                                 unsigned short* __restrict__ w1t) {
  int t = blockIdx.x * 256 + threadIdx.x;   // [0, 104*256)
  int r = t & 255;                          // row 0..255
  int j = t >> 8;                           // byte group (kq) 0..103
  unsigned short vals[8];
#pragma unroll
  for (int k = 0; k < 8; ++k) vals[k] = 0;
  if (j < 98) {
    unsigned int v = (unsigned int)w1p[r * 98 + j];
    unsigned int m = (unsigned int)m1p[r * 98 + j];
#pragma unroll
    for (int k = 0; k < 8; ++k) {           // MSB-first per byte (matches _unpack)
      unsigned int bit = (v >> (7 - k)) & 1u;
      unsigned int mk  = (m >> (7 - k)) & 1u;
      vals[k] = (unsigned short)(mk ? (bit ? 0x3F80u : 0xBF80u) : 0u);  // +1/-1/0
    }
  }
  uint4 pack;
  pack.x = (unsigned)vals[0] | ((unsigned)vals[1] << 16);
  pack.y = (unsigned)vals[2] | ((unsigned)vals[3] << 16);
  pack.z = (unsigned)vals[4] | ((unsigned)vals[5] << 16);
  pack.w = (unsigned)vals[6] | ((unsigned)vals[7] << 16);
  *reinterpret_cast<uint4*>(w1t + t * 8) = pack;
}

// ---------------------------------------------------------------------------
// Kernel 2: fused  h = relu(a1 * x@W1^T);  out = a2 * (h@W2^T)
// v8: OCCUPANCY experiment. BM=32, 512 thr (8 waves), grid 1024, K in two
// halves so LDS = 26.6 KB/block and regs fit a 64-VGPR cap:
// __launch_bounds__(512, 8) -> 4 resident blocks/CU = 32 waves/CU (FULL).
// Cross-block phase stagger provides the stage||compute overlap that
// intra-block scheduling (v5/v6/v7, all ~46-52us) failed to deliver.
// W fragments stream straight from L2-resident fragment-transposed w1t.
//   A-frag: A[m=l15][k=quad*8+j]; B-frag: B^T[n=l15][k=quad*8+j];
//   C/D: col=l15, row=quad*4+reg  (m89-verified layouts).
// ---------------------------------------------------------------------------
#define BM 32
#define HS_LD 264    // 256 + 8 pad: layer-2 Hs reads conflict-free
#define W2_LD 264

// phase-1 LDS (shorts): Xs[52][32][8] = 13312 shorts = 26624 B (one K-half)
// phase-2 overlay:      Hs[32][264] = 8448 @ 0,  W2s[16][264] @ 8448 (end 12672)
#define OFF_W2 8448

__global__ __launch_bounds__(512, 8) void fused_kernel(
    const float* __restrict__ x,
    const unsigned short* __restrict__ w1t,
    const int* __restrict__ w2p,
    const int* __restrict__ m2p,
    const float* __restrict__ a1p,
    const float* __restrict__ a2p,
    float* __restrict__ out) {
  __shared__ unsigned short smem[13312];   // 26624 B

  const int tid  = threadIdx.x;
  const int wave = tid >> 6;
  const int lane = tid & 63;
  const int l15  = lane & 15;
  const int quad = lane >> 4;
  const int row0 = blockIdx.x * BM;

  floatx4 acc[2][2];
#pragma unroll
  for (int i = 0; i < 2; ++i)
#pragma unroll
    for (int j = 0; j < 2; ++j) acc[i][j] = (floatx4){0.f, 0.f, 0.f, 0.f};

  // x staging coords: 16 threads per row, 7 float4-groups per thread (guarded)
  const int sr = tid >> 4;          // row 0..31
  const int g0 = tid & 15;          // group base 0..15
  const float* xrow = x + (size_t)(row0 + sr) * 784;

  auto stage_half = [&](int sp) {
    float4 xv[7];
#pragma unroll
    for (int it = 0; it < 7; ++it) {
      int g = g0 + it * 16;                 // local group 0..111
      int col = sp * 416 + g * 4;
      if (g < 104 && col < 784)
        xv[it] = *reinterpret_cast<const float4*>(xrow + col);
      else
        xv[it] = (float4){0.f, 0.f, 0.f, 0.f};
    }
#pragma unroll
    for (int it = 0; it < 7; ++it) {
      int g = g0 + it * 16;
      if (g < 104) {
        ushort4 b;
        b.x = f2bf(xv[it].x); b.y = f2bf(xv[it].y);
        b.z = f2bf(xv[it].z); b.w = f2bf(xv[it].w);
        // Xs[kq = g>>1][row sr][half g&1]
        *reinterpret_cast<ushort4*>(&smem[(g >> 1) * 256 + sr * 8 + (g & 1) * 4]) = b;
      }
    }
  };

  // W fragment base: B-frag row n = wave*32 + nj*16 + l15 (wave covers 32 cols)
  const unsigned short* wl = w1t + ((size_t)wave * 32 + l15) * 8;

  auto compute_half = [&](int hb) {
#pragma unroll
    for (int cl = 0; cl < 13; ++cl) {
      const int cg = hb * 13 + cl;          // global chunk
      bf16x8 af[2], bfv[2];
#pragma unroll
      for (int nj = 0; nj < 2; ++nj)
        bfv[nj] = *reinterpret_cast<const bf16x8*>(
            wl + (size_t)(cg * 4 + quad) * 2048 + nj * 128);
#pragma unroll
      for (int mi = 0; mi < 2; ++mi)
        af[mi] = *reinterpret_cast<const bf16x8*>(
            &smem[(cl * 4 + quad) * 256 + (mi * 16 + l15) * 8]);
#pragma unroll
      for (int mi = 0; mi < 2; ++mi)
#pragma unroll
        for (int nj = 0; nj < 2; ++nj)
          acc[mi][nj] = __builtin_amdgcn_mfma_f32_16x16x32_bf16(
              af[mi], bfv[nj], acc[mi][nj], 0, 0, 0);
    }
  };

  stage_half(0);
  __syncthreads();       // half-0 ready
  compute_half(0);
  __syncthreads();       // all waves done reading half-0
  stage_half(1);
  __syncthreads();       // half-1 ready
  compute_half(1);
  __syncthreads();       // done reading Xs before Hs overlay

  // ---- epilogue layer 1: h = relu(a1*acc) -> Hs bf16 (overlays Xs) ----
  const float a1 = a1p[0];
  const float a2 = a2p[0];
#pragma unroll
  for (int mi = 0; mi < 2; ++mi) {
#pragma unroll
    for (int nj = 0; nj < 2; ++nj) {
      int col   = wave * 32 + nj * 16 + l15;
      int rbase = mi * 16 + quad * 4;
#pragma unroll
      for (int rr = 0; rr < 4; ++rr) {
        float h = fmaxf(a1 * acc[mi][nj][rr], 0.f);
        smem[(rbase + rr) * HS_LD + col] = f2bf(h);
      }
    }
  }
  // ---- decode w2 -> W2s[16][264] (rows 10..15 zero) ----
  if (tid < 320) {
    int rr = tid >> 5, j = tid & 31;
    unsigned int v = (unsigned int)w2p[rr * 32 + j];
    unsigned int m = (unsigned int)m2p[rr * 32 + j];
#pragma unroll
    for (int k = 0; k < 8; ++k) {
      unsigned int bit = (v >> (7 - k)) & 1u;
      unsigned int mk  = (m >> (7 - k)) & 1u;
      smem[OFF_W2 + rr * W2_LD + j * 8 + k] =
          (unsigned short)(mk ? (bit ? 0x3F80u : 0xBF80u) : 0u);
    }
  }
  for (int idx = tid; idx < 6 * 256; idx += 512) {
    int rr = 10 + (idx >> 8), c = idx & 255;
    smem[OFF_W2 + rr * W2_LD + c] = 0;
  }
  __syncthreads();

  // ---- layer 2: out[32][10] = Hs @ W2s^T; waves 0..1, 16 rows each, K=256 ----
  if (wave < 2) {
    floatx4 o2 = (floatx4){0.f, 0.f, 0.f, 0.f};
#pragma unroll
    for (int ks = 0; ks < 8; ++ks) {
      bf16x8 ha = *reinterpret_cast<const bf16x8*>(
          &smem[(wave * 16 + l15) * HS_LD + ks * 32 + quad * 8]);
      bf16x8 wb = *reinterpret_cast<const bf16x8*>(
          &smem[OFF_W2 + l15 * W2_LD + ks * 32 + quad * 8]);
      o2 = __builtin_amdgcn_mfma_f32_16x16x32_bf16(ha, wb, o2, 0, 0, 0);
    }
    if (l15 < 10) {
#pragma unroll
      for (int rr = 0; rr < 4; ++rr) {
        int gr = row0 + wave * 16 + quad * 4 + rr;
        out[(size_t)gr * 10 + l15] = a2 * o2[rr];
      }
    }
  }
}

extern "C" void kernel_launch(void* const* d_in, const int* in_sizes, int n_in,
                              void* d_out, int out_size, void* d_ws, size_t ws_size,
                              hipStream_t stream) {
  const float* x   = (const float*)d_in[0];
  const int*   w1p = (const int*)d_in[1];
  const int*   m1p = (const int*)d_in[2];
  const float* a1  = (const float*)d_in[3];
  const int*   w2p = (const int*)d_in[4];
  const int*   m2p = (const int*)d_in[5];
  const float* a2  = (const float*)d_in[6];
  unsigned short* w1t = (unsigned short*)d_ws;  // 104*256*8 bf16 = 416 KB scratch
  float* out = (float*)d_out;

  decode_w1_kernel<<<104, 256, 0, stream>>>(w1p, m1p, w1t);
  fused_kernel<<<1024, 512, 0, stream>>>(x, w1t, w2p, m2p, a1, a2, out);
}